// Round 1
// baseline (1193.383 us; speedup 1.0000x reference)
//
#include <hip/hip_runtime.h>
#include <hip/hip_fp16.h>

// Problem constants
constexpr int BATCH = 4;
constexpr int CH    = 256;   // c
constexpr int N     = 4096;  // h*w (64*64)
constexpr int CIN   = 1024;  // c + 768
constexpr int KC    = 512;   // 2c
constexpr float SM_NEG = -60000.0f;

// GEMM tiling
constexpr int BM = 64, BN = 64, BK = 16;
constexpr int LDP = BM + 4;  // padded LDS stride (68) -> keeps float4 LDS reads aligned

// Workspace layout (bytes). Total ~169 MB.
constexpr size_t OFF_M    = 0;                                    // BATCH*N f32 (fg mask)
constexpr size_t OFF_VIS  = OFF_M   + (size_t)BATCH * N * 4;      // BATCH*N f32 (visatt)
constexpr size_t OFF_MAXV = OFF_VIS + (size_t)BATCH * N * 4;      // 1 f32 (padded)
constexpr size_t OFF_FN   = OFF_MAXV + 1024;                      // BATCH*CH*N f32 (feats -> normalized)
constexpr size_t OFF_AF   = OFF_FN  + (size_t)BATCH * CH * N * 4; // BATCH*CH*N f32 (att_fore)
constexpr size_t OFF_ATT  = OFF_AF  + (size_t)BATCH * CH * N * 4; // BATCH*N*N fp16 (scores -> att)
constexpr size_t OFF_PART = OFF_ATT + (size_t)BATCH * N * N * 2;  // 16*BATCH*N f32 (colsum partials)

// ---------------------------------------------------------------- maskpool
__global__ void k_maskpool(const float* __restrict__ mask, float* __restrict__ m)
{
    int idx = blockIdx.x * 256 + threadIdx.x;   // [0, BATCH*N)
    int b = idx >> 12, p = idx & 4095;
    int y = p >> 6, x = p & 63;
    const float* base = mask + (size_t)b * 512 * 512 + (y * 8) * 512 + x * 8;
    float mx = 0.f;
    for (int dy = 0; dy < 8; dy++) {
        #pragma unroll
        for (int dx = 0; dx < 8; dx++) mx = fmaxf(mx, base[dy * 512 + dx]);
    }
    m[idx] = (mx > 0.f) ? 1.f : 0.f;
}

// ---------------------------------------------------------------- feats = K_w @ [x; dvt] + K_b
__global__ __launch_bounds__(256) void k_feats_gemm(
    const float* __restrict__ x, const float* __restrict__ dvt,
    const float* __restrict__ Kw, const float* __restrict__ Kb,
    float* __restrict__ feats)
{
    __shared__ float As[BK][LDP];
    __shared__ float Bs[BK][LDP];
    const int b  = blockIdx.z;
    const int n0 = blockIdx.x * BN;
    const int m0 = blockIdx.y * BM;
    const int t  = threadIdx.x;
    const int tx = t & 15, ty = t >> 4;
    const float* xb = x   + (size_t)b * CH  * N;
    const float* db = dvt + (size_t)b * 768 * N;
    float acc[4][4] = {};
    const int amm = t >> 2, akk = (t & 3) * 4;
    const int bnn = t & 63, bk0 = t >> 6;
    for (int k0 = 0; k0 < CIN; k0 += BK) {
        float4 av = *(const float4*)(Kw + (size_t)(m0 + amm) * CIN + k0 + akk);
        As[akk + 0][amm] = av.x; As[akk + 1][amm] = av.y;
        As[akk + 2][amm] = av.z; As[akk + 3][amm] = av.w;
        #pragma unroll
        for (int r = 0; r < 4; r++) {
            int kk = bk0 + r * 4;
            int ch = k0 + kk;
            Bs[kk][bnn] = (ch < CH) ? xb[(size_t)ch * N + n0 + bnn]
                                    : db[(size_t)(ch - CH) * N + n0 + bnn];
        }
        __syncthreads();
        #pragma unroll
        for (int kk = 0; kk < BK; kk++) {
            float4 a  = *(const float4*)&As[kk][ty * 4];
            float4 bb = *(const float4*)&Bs[kk][tx * 4];
            float ar[4] = {a.x, a.y, a.z, a.w};
            float br[4] = {bb.x, bb.y, bb.z, bb.w};
            #pragma unroll
            for (int i = 0; i < 4; i++)
                #pragma unroll
                for (int j = 0; j < 4; j++)
                    acc[i][j] += ar[i] * br[j];
        }
        __syncthreads();
    }
    float* ob = feats + (size_t)b * CH * N;
    #pragma unroll
    for (int i = 0; i < 4; i++) {
        int mm = m0 + ty * 4 + i;
        float bias = Kb[mm];
        float4 o;
        o.x = acc[i][0] + bias; o.y = acc[i][1] + bias;
        o.z = acc[i][2] + bias; o.w = acc[i][3] + bias;
        *(float4*)(ob + (size_t)mm * N + n0 + tx * 4) = o;
    }
}

// ---------------------------------------------------------------- per-position channel L2 normalize (in place)
__global__ void k_normalize(float* __restrict__ Fn)
{
    int idx = blockIdx.x * 64 + threadIdx.x;   // [0, BATCH*N)
    int b = idx >> 12, p = idx & 4095;
    float* f = Fn + (size_t)b * CH * N + p;
    float s = 0.f;
    for (int c = 0; c < CH; c++) { float v = f[(size_t)c * N]; s += v * v; }
    float inv = 1.f / (sqrtf(s) + 1e-8f);
    for (int c = 0; c < CH; c++) f[(size_t)c * N] *= inv;
}

// ---------------------------------------------------------------- S[q][k] = 20 * Fn[:,q] . Fn[:,k]  (fp16)
__global__ __launch_bounds__(256) void k_score_gemm(
    const float* __restrict__ Fn, __half* __restrict__ att)
{
    __shared__ float As[BK][LDP];
    __shared__ float Bs[BK][LDP];
    const int b   = blockIdx.z;
    const int k0n = blockIdx.x * BN;   // key dim
    const int q0  = blockIdx.y * BM;   // query dim
    const int t   = threadIdx.x;
    const int tx  = t & 15, ty = t >> 4;
    const float* F = Fn + (size_t)b * CH * N;
    float acc[4][4] = {};
    const int lkk = t >> 4, lmm = (t & 15) * 4;
    for (int c0 = 0; c0 < CH; c0 += BK) {
        const float* Frow = F + (size_t)(c0 + lkk) * N;
        *(float4*)&As[lkk][lmm] = *(const float4*)(Frow + q0  + lmm);
        *(float4*)&Bs[lkk][lmm] = *(const float4*)(Frow + k0n + lmm);
        __syncthreads();
        #pragma unroll
        for (int kk = 0; kk < BK; kk++) {
            float4 a  = *(const float4*)&As[kk][ty * 4];
            float4 bb = *(const float4*)&Bs[kk][tx * 4];
            float ar[4] = {a.x, a.y, a.z, a.w};
            float br[4] = {bb.x, bb.y, bb.z, bb.w};
            #pragma unroll
            for (int i = 0; i < 4; i++)
                #pragma unroll
                for (int j = 0; j < 4; j++)
                    acc[i][j] += ar[i] * br[j];
        }
        __syncthreads();
    }
    __half* ab = att + (size_t)b * N * N;
    #pragma unroll
    for (int i = 0; i < 4; i++) {
        int q = q0 + ty * 4 + i;
        __half2 h0 = __floats2half2_rn(20.f * acc[i][0], 20.f * acc[i][1]);
        __half2 h1 = __floats2half2_rn(20.f * acc[i][2], 20.f * acc[i][3]);
        __half2* p2 = (__half2*)(ab + (size_t)q * N + k0n + tx * 4);
        p2[0] = h0; p2[1] = h1;
    }
}

// ---------------------------------------------------------------- row softmax over bg keys, in place
__global__ __launch_bounds__(256) void k_softmax(
    const float* __restrict__ m, __half* __restrict__ att)
{
    const int b = blockIdx.x >> 12, q = blockIdx.x & 4095;
    const float* mb = m + (size_t)b * N;
    __half* row = att + ((size_t)b * N + q) * N;
    __shared__ float sm_[N];
    __shared__ float red[256];
    const int t = threadIdx.x;
    #pragma unroll
    for (int j = 0; j < 16; j++) sm_[t + j * 256] = mb[t + j * 256];
    __syncthreads();
    const bool fg = (sm_[q] != 0.f);
    float v[16]; bool valid[16];
    float mx = -1e30f;
    #pragma unroll
    for (int j = 0; j < 16; j++) {
        int k = t + j * 256;
        v[j] = __half2float(row[k]);
        valid[j] = (sm_[k] == 0.f);
        if (valid[j]) mx = fmaxf(mx, v[j]);
    }
    red[t] = mx; __syncthreads();
    for (int s = 128; s > 0; s >>= 1) { if (t < s) red[t] = fmaxf(red[t], red[t + s]); __syncthreads(); }
    mx = red[0]; __syncthreads();
    float sum = 0.f;
    #pragma unroll
    for (int j = 0; j < 16; j++) {
        if (valid[j]) { v[j] = __expf(v[j] - mx); sum += v[j]; } else v[j] = 0.f;
    }
    red[t] = sum; __syncthreads();
    for (int s = 128; s > 0; s >>= 1) { if (t < s) red[t] += red[t + s]; __syncthreads(); }
    sum = red[0];
    float inv = (fg && sum > 0.f) ? 1.f / sum : 0.f;
    #pragma unroll
    for (int j = 0; j < 16; j++) row[t + j * 256] = __float2half(v[j] * inv);
}

// ---------------------------------------------------------------- visatt[k] = sum_q att[q][k]  (two stage)
__global__ void k_colsum_part(const __half* __restrict__ att, float* __restrict__ part)
{
    int idx = blockIdx.x * 256 + threadIdx.x;   // b*N
    int b = idx >> 12, k = idx & 4095;
    int qc = blockIdx.y;
    const __half* A = att + (size_t)b * N * N + k;
    float s = 0.f;
    for (int q = qc * 256; q < qc * 256 + 256; q++) s += __half2float(A[(size_t)q * N]);
    part[(size_t)qc * BATCH * N + idx] = s;
}

__global__ void k_colsum_final(const float* __restrict__ part, float* __restrict__ vis)
{
    int idx = blockIdx.x * 256 + threadIdx.x;
    float s = 0.f;
    #pragma unroll
    for (int j = 0; j < 16; j++) s += part[(size_t)j * BATCH * N + idx];
    vis[idx] = s;
}

// ---------------------------------------------------------------- global max of visatt
__global__ void k_vismax(const float* __restrict__ vis, float* __restrict__ maxv)
{
    __shared__ float red[256];
    int t = threadIdx.x;
    float mx = 0.f;
    for (int i = t; i < BATCH * N; i += 256) mx = fmaxf(mx, vis[i]);
    red[t] = mx; __syncthreads();
    for (int s = 128; s > 0; s >>= 1) { if (t < s) red[t] = fmaxf(red[t], red[t + s]); __syncthreads(); }
    if (t == 0) maxv[0] = red[0];
}

// ---------------------------------------------------------------- AF[c][q] = sum_k (x*bm)[c][k] * att[q][k]
__global__ __launch_bounds__(256) void k_att_fore(
    const float* __restrict__ x, const float* __restrict__ m,
    const __half* __restrict__ att, float* __restrict__ AF)
{
    __shared__ float As[BK][LDP];
    __shared__ float Bs[BK][LDP];
    const int b  = blockIdx.z;
    const int q0 = blockIdx.x * BN;   // N dim = q
    const int m0 = blockIdx.y * BM;   // M dim = c
    const int t  = threadIdx.x;
    const int tx = t & 15, ty = t >> 4;
    const float* xb = x + (size_t)b * CH * N;
    const float* mb = m + (size_t)b * N;
    const __half* ab = att + (size_t)b * N * N;
    float acc[4][4] = {};
    const int amm = t >> 2, akk = (t & 3) * 4;
    for (int k0 = 0; k0 < N; k0 += BK) {
        float4 av = *(const float4*)(xb + (size_t)(m0 + amm) * N + k0 + akk);
        float4 mk = *(const float4*)(mb + k0 + akk);
        As[akk + 0][amm] = av.x * (1.f - mk.x);
        As[akk + 1][amm] = av.y * (1.f - mk.y);
        As[akk + 2][amm] = av.z * (1.f - mk.z);
        As[akk + 3][amm] = av.w * (1.f - mk.w);
        const __half2* p2 = (const __half2*)(ab + (size_t)(q0 + amm) * N + k0 + akk);
        __half2 h0 = p2[0], h1 = p2[1];
        float2 f0 = __half22float2(h0), f1 = __half22float2(h1);
        Bs[akk + 0][amm] = f0.x; Bs[akk + 1][amm] = f0.y;
        Bs[akk + 2][amm] = f1.x; Bs[akk + 3][amm] = f1.y;
        __syncthreads();
        #pragma unroll
        for (int kk = 0; kk < BK; kk++) {
            float4 a  = *(const float4*)&As[kk][ty * 4];
            float4 bb = *(const float4*)&Bs[kk][tx * 4];
            float ar[4] = {a.x, a.y, a.z, a.w};
            float br[4] = {bb.x, bb.y, bb.z, bb.w};
            #pragma unroll
            for (int i = 0; i < 4; i++)
                #pragma unroll
                for (int j = 0; j < 4; j++)
                    acc[i][j] += ar[i] * br[j];
        }
        __syncthreads();
    }
    float* ob = AF + (size_t)b * CH * N;
    #pragma unroll
    for (int i = 0; i < 4; i++) {
        float4 o; o.x = acc[i][0]; o.y = acc[i][1]; o.z = acc[i][2]; o.w = acc[i][3];
        *(float4*)(ob + (size_t)(m0 + ty * 4 + i) * N + q0 + tx * 4) = o;
    }
}

// ---------------------------------------------------------------- fused = fuse_w @ [AF; x]; out = blend
__global__ __launch_bounds__(256) void k_fused_out(
    const float* __restrict__ x, const float* __restrict__ m,
    const float* __restrict__ AF, const float* __restrict__ fw,
    float* __restrict__ out)
{
    __shared__ float As[BK][LDP];
    __shared__ float Bs[BK][LDP];
    const int b  = blockIdx.z;
    const int n0 = blockIdx.x * BN;
    const int m0 = blockIdx.y * BM;
    const int t  = threadIdx.x;
    const int tx = t & 15, ty = t >> 4;
    const float* xb = x  + (size_t)b * CH * N;
    const float* ab = AF + (size_t)b * CH * N;
    const float* mb = m  + (size_t)b * N;
    float acc[4][4] = {};
    const int amm = t >> 2, akk = (t & 3) * 4;
    const int bnn = t & 63, bk0 = t >> 6;
    for (int k0 = 0; k0 < KC; k0 += BK) {
        float4 av = *(const float4*)(fw + (size_t)(m0 + amm) * KC + k0 + akk);
        As[akk + 0][amm] = av.x; As[akk + 1][amm] = av.y;
        As[akk + 2][amm] = av.z; As[akk + 3][amm] = av.w;
        #pragma unroll
        for (int r = 0; r < 4; r++) {
            int kk = bk0 + r * 4;
            int ch = k0 + kk;
            Bs[kk][bnn] = (ch < CH) ? ab[(size_t)ch * N + n0 + bnn]
                                    : xb[(size_t)(ch - CH) * N + n0 + bnn];
        }
        __syncthreads();
        #pragma unroll
        for (int kk = 0; kk < BK; kk++) {
            float4 a  = *(const float4*)&As[kk][ty * 4];
            float4 bb = *(const float4*)&Bs[kk][tx * 4];
            float ar[4] = {a.x, a.y, a.z, a.w};
            float br[4] = {bb.x, bb.y, bb.z, bb.w};
            #pragma unroll
            for (int i = 0; i < 4; i++)
                #pragma unroll
                for (int j = 0; j < 4; j++)
                    acc[i][j] += ar[i] * br[j];
        }
        __syncthreads();
    }
    float* ob = out + (size_t)b * CH * N;
    #pragma unroll
    for (int i = 0; i < 4; i++) {
        int mm = m0 + ty * 4 + i;
        #pragma unroll
        for (int j = 0; j < 4; j++) {
            int p = n0 + tx * 4 + j;
            float mv = mb[p];
            ob[(size_t)mm * N + p] = (mv != 0.f) ? acc[i][j] : xb[(size_t)mm * N + p];
        }
    }
}

// ---------------------------------------------------------------- attmask = upsample8(visatt) / max
__global__ void k_attmask(const float* __restrict__ vis, const float* __restrict__ maxv,
                          float* __restrict__ amask)
{
    int idx = blockIdx.x * 256 + threadIdx.x;   // [0, BATCH*512*512)
    int b = idx >> 18;
    int r = idx & 262143;
    int Y = r >> 9, X = r & 511;
    amask[idx] = vis[(size_t)b * N + (Y >> 3) * 64 + (X >> 3)] / maxv[0];
}

// ---------------------------------------------------------------- launch
extern "C" void kernel_launch(void* const* d_in, const int* in_sizes, int n_in,
                              void* d_out, int out_size, void* d_ws, size_t ws_size,
                              hipStream_t stream)
{
    const float* x    = (const float*)d_in[0];
    const float* mask = (const float*)d_in[1];
    const float* dvt  = (const float*)d_in[2];
    const float* Kw   = (const float*)d_in[3];
    const float* Kb   = (const float*)d_in[4];
    const float* fw   = (const float*)d_in[5];
    float* out = (float*)d_out;

    char* ws = (char*)d_ws;
    float*  m    = (float*) (ws + OFF_M);
    float*  vis  = (float*) (ws + OFF_VIS);
    float*  maxv = (float*) (ws + OFF_MAXV);
    float*  Fn   = (float*) (ws + OFF_FN);
    float*  AF   = (float*) (ws + OFF_AF);
    __half* att  = (__half*)(ws + OFF_ATT);
    float*  part = (float*) (ws + OFF_PART);

    k_maskpool  <<<dim3(BATCH * N / 256), dim3(256), 0, stream>>>(mask, m);
    k_feats_gemm<<<dim3(N / BN, CH / BM, BATCH), dim3(256), 0, stream>>>(x, dvt, Kw, Kb, Fn);
    k_normalize <<<dim3(BATCH * N / 64), dim3(64), 0, stream>>>(Fn);
    k_score_gemm<<<dim3(N / BN, N / BM, BATCH), dim3(256), 0, stream>>>(Fn, att);
    k_softmax   <<<dim3(BATCH * N), dim3(256), 0, stream>>>(m, att);
    k_colsum_part<<<dim3(BATCH * N / 256, 16), dim3(256), 0, stream>>>(att, part);
    k_colsum_final<<<dim3(BATCH * N / 256), dim3(256), 0, stream>>>(part, vis);
    k_vismax    <<<dim3(1), dim3(256), 0, stream>>>(vis, maxv);
    k_att_fore  <<<dim3(N / BN, CH / BM, BATCH), dim3(256), 0, stream>>>(x, m, att, AF);
    k_fused_out <<<dim3(N / BN, CH / BM, BATCH), dim3(256), 0, stream>>>(x, m, AF, fw, out);
    k_attmask   <<<dim3(BATCH * 512 * 512 / 256), dim3(256), 0, stream>>>(vis, maxv, out + (size_t)BATCH * CH * N);
}

// Round 2
// 297.931 us; speedup vs baseline: 4.0056x; 4.0056x over previous
//
#include <hip/hip_runtime.h>
#include <hip/hip_bf16.h>

typedef __attribute__((ext_vector_type(8))) short short8;
typedef __attribute__((ext_vector_type(4))) float f32x4;
typedef unsigned int uint;
typedef unsigned short ushort;

constexpr int BATCH = 4;
constexpr int CH    = 256;
constexpr int N     = 4096;   // 64*64
constexpr int DVC   = 768;
constexpr int CIN   = 1024;   // CH + DVC
constexpr int KC    = 512;    // 2*CH

// ---------------- workspace layout (bytes), total ~162 MB ----------------
constexpr size_t OFF_M    = 0;                    // 16384 f32
constexpr size_t OFF_INV  = 64ull << 10;          // 16384 f32
constexpr size_t OFF_VIS  = 128ull << 10;         // 16384 f32
constexpr size_t OFF_MAXV = 192ull << 10;         // 1 f32
constexpr size_t OFF_PART = 256ull << 10;         // 8*16384 f32 = 512KB
constexpr size_t OFF_KWB  = 1ull << 20;           // 256*1024 bf16 = 512KB
constexpr size_t OFF_FWB  = OFF_KWB + (512ull << 10); // 256*512 bf16 = 256KB
constexpr size_t OFF_XT   = 2ull << 20;           // [b][n][256] bf16 = 8MB
constexpr size_t OFF_DVTT = 10ull << 20;          // [b][n][768] bf16 = 24MB (reused later)
constexpr size_t OFF_FNTB = OFF_DVTT;             //   [b][n][256] bf16 = 8MB (after feats)
constexpr size_t OFF_AFT  = OFF_DVTT + (8ull << 20);  // [b][q][256] bf16 = 8MB
constexpr size_t OFF_XB   = OFF_DVTT + (16ull << 20); // [b][c][n]  bf16 = 8MB
constexpr size_t OFF_P    = 34ull << 20;          // [b][q][k] bf16 = 128MB
constexpr size_t OFF_FNT  = OFF_P;                // [b][n][256] f32 = 16MB (early, dead before score)

// ---------------- helpers ----------------
__device__ __forceinline__ ushort f2bf(float f) {
    __hip_bfloat16 h = __float2bfloat16(f);
    return __builtin_bit_cast(ushort, h);
}
__device__ __forceinline__ float bf2f(ushort u) {
    uint v = (uint)u << 16;
    return __builtin_bit_cast(float, v);
}

typedef const __attribute__((address_space(1))) uint* gptr_t;
typedef __attribute__((address_space(3))) uint* lptr_t;
__device__ __forceinline__ void gload_lds16(const void* g, void* l) {
    __builtin_amdgcn_global_load_lds((gptr_t)g, (lptr_t)l, 16, 0, 0);
}

// ---------------- shared GEMM mainloop ----------------
// C[m][n] = sum_k A[m][k]*B'[n][k], bf16 operands, tiles BMx64 / BNx64 in LDS (linear).
// B source splits at k = kend0 (B0 ld=ldb0 for k<kend0, B1 ld=ldb1 for k>=kend0).
template<int WM, int WN>
__device__ __forceinline__ void gemm_core(
    const ushort* __restrict__ A0, int lda, int m0,
    const ushort* __restrict__ B0, int ldb0, int kend0,
    const ushort* __restrict__ B1, int ldb1,
    int n0, int K,
    ushort* AsL, ushort* BsL, f32x4 acc[4][4])
{
    constexpr int NW = WM * WN, BM = WM * 64, BN = WN * 64;
    const int t = threadIdx.x, lane = t & 63, wid = t >> 6;
    const int wm = (wid / WN) * 64, wn = (wid % WN) * 64;

    for (int k0 = 0; k0 < K; k0 += 64) {
        #pragma unroll
        for (int c = wid; c < BM / 8; c += NW) {
            const ushort* g = A0 + (size_t)(m0 + c * 8 + (lane >> 3)) * lda + (k0 + (lane & 7) * 8);
            gload_lds16(g, AsL + c * 512);
        }
        const ushort* Bsrc = (k0 < kend0) ? B0 : B1;
        const int ldb = (k0 < kend0) ? ldb0 : ldb1;
        const int kc  = (k0 < kend0) ? k0 : (k0 - kend0);
        #pragma unroll
        for (int c = wid; c < BN / 8; c += NW) {
            const ushort* g = Bsrc + (size_t)(n0 + c * 8 + (lane >> 3)) * ldb + (kc + (lane & 7) * 8);
            gload_lds16(g, BsL + c * 512);
        }
        __syncthreads();   // drains vmcnt (compiler emits waitcnt before barrier)

        const int ra = wm + (lane & 15), rb = wn + (lane & 15), ko = (lane >> 4) * 8;
        #pragma unroll
        for (int kk = 0; kk < 64; kk += 32) {
            short8 a[4], b[4];
            #pragma unroll
            for (int i = 0; i < 4; i++) a[i] = *(const short8*)(AsL + (ra + i * 16) * 64 + kk + ko);
            #pragma unroll
            for (int j = 0; j < 4; j++) b[j] = *(const short8*)(BsL + (rb + j * 16) * 64 + kk + ko);
            #pragma unroll
            for (int i = 0; i < 4; i++)
                #pragma unroll
                for (int j = 0; j < 4; j++)
                    acc[i][j] = __builtin_amdgcn_mfma_f32_16x16x32_bf16(a[i], b[j], acc[i][j], 0, 0, 0);
        }
        __syncthreads();
    }
}

__device__ __forceinline__ void zero_acc(f32x4 acc[4][4]) {
    f32x4 z = {0.f, 0.f, 0.f, 0.f};
    #pragma unroll
    for (int i = 0; i < 4; i++)
        #pragma unroll
        for (int j = 0; j < 4; j++) acc[i][j] = z;
}

// ---------------- small kernels ----------------
__global__ void k_maskpool(const float* __restrict__ mask, float* __restrict__ m)
{
    int idx = blockIdx.x * 256 + threadIdx.x;
    int b = idx >> 12, p = idx & 4095;
    int y = p >> 6, x = p & 63;
    const float* base = mask + (size_t)b * 512 * 512 + (y * 8) * 512 + x * 8;
    float mx = 0.f;
    for (int dy = 0; dy < 8; dy++) {
        #pragma unroll
        for (int dx = 0; dx < 8; dx++) mx = fmaxf(mx, base[dy * 512 + dx]);
    }
    m[idx] = (mx > 0.f) ? 1.f : 0.f;
}

__global__ void k_wconv(const float* __restrict__ Kw, const float* __restrict__ fw,
                        ushort* __restrict__ Kwb, ushort* __restrict__ fwb)
{
    int i = blockIdx.x * 256 + threadIdx.x;   // [0, 393216)
    if (i < CH * CIN) Kwb[i] = f2bf(Kw[i]);
    else              fwb[i - CH * CIN] = f2bf(fw[i - CH * CIN]);
}

// transpose f32 [b][C][4096] -> bf16 [b][4096][C]
__global__ __launch_bounds__(256) void k_tr(const float* __restrict__ src,
                                            ushort* __restrict__ dst, int C)
{
    __shared__ float Ls[64][65];
    const int ci0 = blockIdx.x * 64, n0 = blockIdx.y * 64, b = blockIdx.z;
    const float* s = src + (size_t)b * C * 4096;
    const int t = threadIdx.x;
    #pragma unroll
    for (int it = 0; it < 4; it++) {
        int f4 = it * 256 + t;
        int r = f4 >> 4, c4 = f4 & 15;
        float4 v = *(const float4*)(s + (size_t)(ci0 + r) * 4096 + n0 + c4 * 4);
        Ls[r][c4 * 4 + 0] = v.x; Ls[r][c4 * 4 + 1] = v.y;
        Ls[r][c4 * 4 + 2] = v.z; Ls[r][c4 * 4 + 3] = v.w;
    }
    __syncthreads();
    ushort* d = dst + (size_t)b * 4096 * C;
    #pragma unroll
    for (int it = 0; it < 8; it++) {
        int p = it * 256 + t;
        int rn = p >> 5, cc2 = p & 31;
        uint val = (uint)f2bf(Ls[cc2 * 2][rn]) | ((uint)f2bf(Ls[cc2 * 2 + 1][rn]) << 16);
        *(uint*)(d + (size_t)(n0 + rn) * C + ci0 + cc2 * 2) = val;
    }
}

__global__ void k_xcvt(const float* __restrict__ x, ushort* __restrict__ xb)
{
    int i4 = blockIdx.x * 256 + threadIdx.x;   // [0, 4.2M/4)
    float4 v = *(const float4*)(x + (size_t)i4 * 4);
    ushort4 o = { f2bf(v.x), f2bf(v.y), f2bf(v.z), f2bf(v.w) };
    *(ushort4*)(xb + (size_t)i4 * 4) = o;
}

// wave per position: L2-normalize FnT f32 [p][256] -> FnTb bf16
__global__ __launch_bounds__(256) void k_normalize(const float* __restrict__ FnT,
                                                   ushort* __restrict__ FnTb)
{
    const int t = threadIdx.x, lane = t & 63, wid = t >> 6;
    const int p = blockIdx.x * 4 + wid;
    const float* src = FnT + (size_t)p * CH;
    float4 v = *(const float4*)(src + lane * 4);
    float s = v.x * v.x + v.y * v.y + v.z * v.z + v.w * v.w;
    #pragma unroll
    for (int m = 1; m < 64; m <<= 1) s += __shfl_xor(s, m);
    float inv = 1.f / (sqrtf(s) + 1e-8f);
    ushort4 o = { f2bf(v.x * inv), f2bf(v.y * inv), f2bf(v.z * inv), f2bf(v.w * inv) };
    *(ushort4*)(FnTb + (size_t)p * CH + lane * 4) = o;
}

// ---------------- GEMM kernels ----------------
// feats: FnT[n][c] (f32) = Kw[c][:] . In[:][n] + Kb[c]
__global__ __launch_bounds__(128) void k_feats(
    const ushort* __restrict__ Kwb, const ushort* __restrict__ xT,
    const ushort* __restrict__ dvtT, const float* __restrict__ Kb,
    float* __restrict__ FnT)
{
    __shared__ ushort SH[(64 + 128) * 64];
    const int b = blockIdx.z;
    const int n0 = blockIdx.x * 128, m0 = blockIdx.y * 64;
    const int lane = threadIdx.x & 63, wid = threadIdx.x >> 6;
    const int wn = (wid & 1) * 64;
    f32x4 acc[4][4]; zero_acc(acc);
    gemm_core<1, 2>(Kwb, CIN, m0,
                    xT + (size_t)b * N * CH, CH, CH,
                    dvtT + (size_t)b * N * DVC, DVC,
                    n0, CIN, SH, SH + 64 * 64, acc);
    float* Fb = FnT + (size_t)b * N * CH;
    #pragma unroll
    for (int i = 0; i < 4; i++) {
        int mbase = m0 + i * 16 + ((lane >> 4) * 4);
        float4 bias = *(const float4*)(Kb + mbase);
        #pragma unroll
        for (int j = 0; j < 4; j++) {
            int n = n0 + wn + j * 16 + (lane & 15);
            float4 o;
            o.x = acc[i][j][0] + bias.x; o.y = acc[i][j][1] + bias.y;
            o.z = acc[i][j][2] + bias.z; o.w = acc[i][j][3] + bias.w;
            *(float4*)(Fb + (size_t)n * CH + mbase) = o;
        }
    }
}

// score: P[q][k] = (1-m[k]) * exp(20*dot - 20)   (bf16, unnormalized)
__global__ __launch_bounds__(256) void k_score(
    const ushort* __restrict__ FnTb, const float* __restrict__ m_,
    ushort* __restrict__ P)
{
    __shared__ ushort SH[(128 + 128) * 64];
    const int b = blockIdx.z;
    const int n0 = blockIdx.x * 128, m0 = blockIdx.y * 128;
    const int t = threadIdx.x, lane = t & 63, wid = t >> 6;
    const int wm = (wid >> 1) * 64, wn = (wid & 1) * 64;
    const ushort* Fb = FnTb + (size_t)b * N * CH;
    f32x4 acc[4][4]; zero_acc(acc);
    gemm_core<2, 2>(Fb, CH, m0, Fb, CH, CH, Fb, CH, n0, CH, SH, SH + 128 * 64, acc);

    const float* mb = m_ + (size_t)b * N;
    float km[4];
    #pragma unroll
    for (int j = 0; j < 4; j++) km[j] = 1.f - mb[n0 + wn + j * 16 + (lane & 15)];

    ushort* Cs = SH;  // 128x128 bf16 repack
    #pragma unroll
    for (int i = 0; i < 4; i++) {
        int rbase = wm + i * 16 + ((lane >> 4) * 4);
        #pragma unroll
        for (int j = 0; j < 4; j++) {
            int cl = wn + j * 16 + (lane & 15);
            #pragma unroll
            for (int r = 0; r < 4; r++) {
                float p = km[j] * __expf(20.f * acc[i][j][r] - 20.f);
                Cs[(rbase + r) * 128 + cl] = f2bf(p);
            }
        }
    }
    __syncthreads();
    ushort* Pb = P + (size_t)b * N * N;
    #pragma unroll
    for (int it = 0; it < 8; it++) {
        int v8 = it * 256 + t;
        int row = v8 >> 4, c8 = (v8 & 15) * 8;
        *(uint4*)(Pb + (size_t)(m0 + row) * N + n0 + c8) = *(const uint4*)(Cs + row * 128 + c8);
    }
}

// rowsum -> inv[q] = m[q] && s>0 ? 1/s : 0
__global__ __launch_bounds__(256) void k_rowsum(
    const ushort* __restrict__ P, const float* __restrict__ m_,
    float* __restrict__ inv)
{
    const int t = threadIdx.x, lane = t & 63, wid = t >> 6;
    const int qg = blockIdx.x * 4 + wid;     // [0,16384)
    const ushort* row = P + (size_t)qg * N;
    float s = 0.f;
    #pragma unroll
    for (int it = 0; it < 8; it++) {
        uint4 v = *(const uint4*)(row + it * 512 + lane * 8);
        const ushort* u = (const ushort*)&v;
        #pragma unroll
        for (int e = 0; e < 8; e++) s += bf2f(u[e]);
    }
    #pragma unroll
    for (int mm = 1; mm < 64; mm <<= 1) s += __shfl_xor(s, mm);
    if (lane == 0)
        inv[qg] = (m_[qg] != 0.f && s > 0.f) ? 1.f / s : 0.f;
}

// att_fore: AFt[q][c] = inv[q] * sum_k xb[c][k]*P[q][k]
__global__ __launch_bounds__(128) void k_att_fore(
    const ushort* __restrict__ xb, const ushort* __restrict__ P,
    const float* __restrict__ inv, ushort* __restrict__ AFt)
{
    __shared__ ushort SH[(64 + 128) * 64];
    const int b = blockIdx.z;
    const int n0 = blockIdx.x * 128, m0 = blockIdx.y * 64;
    const int lane = threadIdx.x & 63, wid = threadIdx.x >> 6;
    const int wn = (wid & 1) * 64;
    const ushort* Pb = P + (size_t)b * N * N;
    f32x4 acc[4][4]; zero_acc(acc);
    gemm_core<1, 2>(xb + (size_t)b * CH * N, N, m0,
                    Pb, N, N, Pb, N,
                    n0, N, SH, SH + 64 * 64, acc);
    const float* invb = inv + (size_t)b * N;
    ushort* Ab = AFt + (size_t)b * N * CH;
    #pragma unroll
    for (int j = 0; j < 4; j++) {
        int q = n0 + wn + j * 16 + (lane & 15);
        float iq = invb[q];
        #pragma unroll
        for (int i = 0; i < 4; i++) {
            int mbase = m0 + i * 16 + ((lane >> 4) * 4);
            ushort4 o = { f2bf(acc[i][j][0] * iq), f2bf(acc[i][j][1] * iq),
                          f2bf(acc[i][j][2] * iq), f2bf(acc[i][j][3] * iq) };
            *(ushort4*)(Ab + (size_t)q * CH + mbase) = o;
        }
    }
}

// fused + blend: out[c][n] = m[n] ? fw[c][:].[AFt;xT][n][:] : x[c][n]
__global__ __launch_bounds__(128) void k_fused(
    const ushort* __restrict__ fwb, const ushort* __restrict__ AFt,
    const ushort* __restrict__ xT, const float* __restrict__ x,
    const float* __restrict__ m_, float* __restrict__ out)
{
    __shared__ ushort SH[(64 + 128) * 64];
    const int b = blockIdx.z;
    const int n0 = blockIdx.x * 128, m0 = blockIdx.y * 64;
    const int lane = threadIdx.x & 63, wid = threadIdx.x >> 6;
    const int wn = (wid & 1) * 64;
    f32x4 acc[4][4]; zero_acc(acc);
    gemm_core<1, 2>(fwb, KC, m0,
                    AFt + (size_t)b * N * CH, CH, CH,
                    xT + (size_t)b * N * CH, CH,
                    n0, KC, SH, SH + 64 * 64, acc);
    const float* mb = m_ + (size_t)b * N;
    const float* xc = x + (size_t)b * CH * N;
    float* ob = out + (size_t)b * CH * N;
    #pragma unroll
    for (int j = 0; j < 4; j++) {
        int n = n0 + wn + j * 16 + (lane & 15);
        float mv = mb[n];
        #pragma unroll
        for (int i = 0; i < 4; i++) {
            int mbase = m0 + i * 16 + ((lane >> 4) * 4);
            #pragma unroll
            for (int r = 0; r < 4; r++) {
                int c = mbase + r;
                ob[(size_t)c * N + n] = (mv != 0.f) ? acc[i][j][r] : xc[(size_t)c * N + n];
            }
        }
    }
}

// ---------------- colsum / vis ----------------
__global__ void k_colsum_part(const ushort* __restrict__ P, const float* __restrict__ inv,
                              float* __restrict__ part)
{
    int g = blockIdx.x * 256 + threadIdx.x;   // [0,16384)
    int b = g >> 12, k = g & 4095;
    int qc = blockIdx.y;                      // 8 chunks of 512
    const ushort* base = P + ((size_t)(b * 4096 + qc * 512)) * 4096 + k;
    const float* ib = inv + b * 4096 + qc * 512;
    float s = 0.f;
    for (int q = 0; q < 512; q++) s += bf2f(base[(size_t)q * 4096]) * ib[q];
    part[(size_t)qc * BATCH * N + g] = s;
}

__global__ void k_colsum_final(const float* __restrict__ part, float* __restrict__ vis)
{
    int g = blockIdx.x * 256 + threadIdx.x;
    float s = 0.f;
    #pragma unroll
    for (int j = 0; j < 8; j++) s += part[(size_t)j * BATCH * N + g];
    vis[g] = s;
}

__global__ void k_vismax(const float* __restrict__ vis, float* __restrict__ maxv)
{
    __shared__ float red[256];
    int t = threadIdx.x;
    float mx = 0.f;
    for (int i = t; i < BATCH * N; i += 256) mx = fmaxf(mx, vis[i]);
    red[t] = mx; __syncthreads();
    for (int s = 128; s > 0; s >>= 1) { if (t < s) red[t] = fmaxf(red[t], red[t + s]); __syncthreads(); }
    if (t == 0) maxv[0] = red[0];
}

__global__ void k_attmask(const float* __restrict__ vis, const float* __restrict__ maxv,
                          float* __restrict__ amask)
{
    int idx = blockIdx.x * 256 + threadIdx.x;
    int b = idx >> 18;
    int r = idx & 262143;
    int Y = r >> 9, X = r & 511;
    amask[idx] = vis[(size_t)b * N + (Y >> 3) * 64 + (X >> 3)] / maxv[0];
}

// ---------------- launch ----------------
extern "C" void kernel_launch(void* const* d_in, const int* in_sizes, int n_in,
                              void* d_out, int out_size, void* d_ws, size_t ws_size,
                              hipStream_t stream)
{
    const float* x    = (const float*)d_in[0];
    const float* mask = (const float*)d_in[1];
    const float* dvt  = (const float*)d_in[2];
    const float* Kw   = (const float*)d_in[3];
    const float* Kb   = (const float*)d_in[4];
    const float* fw   = (const float*)d_in[5];
    float* out = (float*)d_out;

    char* ws = (char*)d_ws;
    float*  m    = (float*)(ws + OFF_M);
    float*  inv  = (float*)(ws + OFF_INV);
    float*  vis  = (float*)(ws + OFF_VIS);
    float*  maxv = (float*)(ws + OFF_MAXV);
    float*  part = (float*)(ws + OFF_PART);
    ushort* Kwb  = (ushort*)(ws + OFF_KWB);
    ushort* fwb  = (ushort*)(ws + OFF_FWB);
    ushort* xT   = (ushort*)(ws + OFF_XT);
    ushort* dvtT = (ushort*)(ws + OFF_DVTT);
    ushort* FnTb = (ushort*)(ws + OFF_FNTB);
    ushort* AFt  = (ushort*)(ws + OFF_AFT);
    ushort* xb   = (ushort*)(ws + OFF_XB);
    ushort* P    = (ushort*)(ws + OFF_P);
    float*  FnT  = (float*)(ws + OFF_FNT);

    k_maskpool   <<<dim3(BATCH * N / 256), 256, 0, stream>>>(mask, m);
    k_wconv      <<<dim3((CH * CIN + CH * KC) / 256), 256, 0, stream>>>(Kw, fw, Kwb, fwb);
    k_tr         <<<dim3(CH / 64, 64, BATCH), 256, 0, stream>>>(x, xT, CH);
    k_tr         <<<dim3(DVC / 64, 64, BATCH), 256, 0, stream>>>(dvt, dvtT, DVC);
    k_feats      <<<dim3(N / 128, CH / 64, BATCH), 128, 0, stream>>>(Kwb, xT, dvtT, Kb, FnT);
    k_xcvt       <<<dim3(BATCH * CH * N / 1024), 256, 0, stream>>>(x, xb);
    k_normalize  <<<dim3(BATCH * N / 4), 256, 0, stream>>>(FnT, FnTb);
    k_score      <<<dim3(N / 128, N / 128, BATCH), 256, 0, stream>>>(FnTb, m, P);
    k_rowsum     <<<dim3(BATCH * N / 4), 256, 0, stream>>>(P, m, inv);
    k_att_fore   <<<dim3(N / 128, CH / 64, BATCH), 128, 0, stream>>>(xb, P, inv, AFt);
    k_colsum_part<<<dim3(BATCH * N / 256, 8), 256, 0, stream>>>(P, inv, part);
    k_colsum_final<<<dim3(BATCH * N / 256), 256, 0, stream>>>(part, vis);
    k_vismax     <<<dim3(1), 256, 0, stream>>>(vis, maxv);
    k_fused      <<<dim3(N / 128, CH / 64, BATCH), 128, 0, stream>>>(fwb, AFt, xT, x, m, out);
    k_attmask    <<<dim3(BATCH * 512 * 512 / 256), 256, 0, stream>>>(vis, maxv, out + (size_t)BATCH * CH * N);
}